// Round 11
// baseline (296.015 us; speedup 1.0000x reference)
//
#include <hip/hip_runtime.h>

#define LOG2E 1.44269504088896340736f
#define LN2F  0.69314718055994530942f

// Fixed problem sizes from the reference setup_inputs()
constexpr int Tn = 1024;          // time steps
constexpr int Bn = 128;           // batch
constexpr int Cn = 96;            // classes
constexpr int Sn = 200;           // max target length
constexpr int Ln = 2 * Sn + 1;    // extended target length = 401
constexpr int W  = 7;             // states per lane (64*7 = 448 >= 401)

__device__ __forceinline__ float fexp2(float x) {
#if __has_builtin(__builtin_amdgcn_exp2f)
    return __builtin_amdgcn_exp2f(x);
#else
    return exp2f(x);
#endif
}
__device__ __forceinline__ float flog2(float x) {
#if __has_builtin(__builtin_amdgcn_logf)
    return __builtin_amdgcn_logf(x);
#else
    return __log2f(x);
#endif
}

// Wave-wide max via DPP (VALU-latency). Result valid in lane 63.
__device__ __forceinline__ float wave_max_dpp_to_lane63(float x) {
    #define DPP_MAX(ctrl)                                                   \
        x = fmaxf(x, __int_as_float(__builtin_amdgcn_update_dpp(            \
                __float_as_int(x), __float_as_int(x), (ctrl), 0xf, 0xf, false)))
    DPP_MAX(0x111);  // row_shr:1
    DPP_MAX(0x112);  // row_shr:2
    DPP_MAX(0x114);  // row_shr:4
    DPP_MAX(0x118);  // row_shr:8
    DPP_MAX(0x142);  // row_bcast15
    DPP_MAX(0x143);  // row_bcast31 -> lane63 = max(all)
    #undef DPP_MAX
    return x;
}

// Emit probability for class c from a register-resident log-prob row:
// qa holds classes [0,64) (lane=class), qb holds classes [64,96) (lane&31).
__device__ __forceinline__ float emit_one(float qa, float qb, int c, bool hi) {
    const float lo = __shfl(qa, c, 64);
    const float h  = __shfl(qb, c & 31, 64);
    return fexp2((hi ? h : lo) * LOG2E);
}

// ---------------------------------------------------------------------------
// FUSED kernel: one wave per batch element does gather + serial recurrence.
// R10 lesson: the separate gather pass + 128 MiB G round-trip WAS the ~100 us
// residue. Here the emit gather (14 bpermutes + 7 exps per row) rides the
// idle LDS-pipe/VALU slots of the latency-bound serial wave, software-
// pipelined TWO steps ahead (em(t+2) prepped at step t) so no ds result is
// consumed sooner than a full step after issue (R8 lesson; also keeps the
// 4-bit lgkmcnt wait satisfied by ops >=1 step old). lp rows prefetched 8
// deep into named registers. Linear-space alpha, band-anchored pow2 rescale,
// consumer-side lane-0 masking — all as validated in R8-R10.
// ---------------------------------------------------------------------------
__global__ __launch_bounds__(64, 1) void ctc_fused_kernel(
    const float* __restrict__ lp,   // [T, B, C]
    const int*   __restrict__ tg,   // [B, S]
    const int*   __restrict__ il,   // [B]
    const int*   __restrict__ tl,   // [B]
    float*       __restrict__ out_pb)
{
    const int b    = blockIdx.x;
    const int lane = threadIdx.x;
    __shared__ float endv[2];

    const int inlen = il[b];
    const int tlen  = tl[b];
    const int ee0 = 2 * tlen - 1;
    const int ee1 = 2 * tlen;

    // Per-lane class constants (0 = blank for even/dead states — harmless).
    int  c0, c1, c2, c3, c4, c5, c6;
    bool h0, h1, h2, h3, h4, h5, h6;
#define MKC(J, CJ, HJ) { const int s_ = lane * W + (J); int c_ = 0;         \
        if (s_ < Ln && (s_ & 1)) c_ = tg[b * Sn + (s_ >> 1)];               \
        CJ = c_; HJ = (c_ >= 64); }
    MKC(0, c0, h0) MKC(1, c1, h1) MKC(2, c2, h2) MKC(3, c3, h3)
    MKC(4, c4, h4) MKC(5, c5, h5) MKC(6, c6, h6)
#undef MKC

    // Skip-transition gate per state (1.0 allowed, 0.0 forbidden).
    auto mk_gate = [&](int j) -> float {
        const int s = lane * W + j;
        if (s < Ln && (s & 1) && s >= 3) {
            const int k = s >> 1;
            if (tg[b * Sn + k] != tg[b * Sn + k - 1]) return 1.0f;
        }
        return 0.0f;
    };
    const float g0 = mk_gate(0), g1 = mk_gate(1), g2 = mk_gate(2),
                g3 = mk_gate(3), g4 = mk_gate(4), g5 = mk_gate(5),
                g6 = mk_gate(6);
    const float zl  = (lane == 0) ? 0.0f : 1.0f;
    const float g1z = g1 * zl;
    const float g0z = g0 * zl;

    const float* src = lp + (size_t)b * Cn;
    constexpr size_t rstride = (size_t)Bn * Cn;
    const int l32 = 64 + (lane & 31);   // classes [64,96) duplicated to lanes 32-63

#define ROWLOAD(QA, QB, T) { const float* rp_ = src + (size_t)(T) * rstride; \
        QA = rp_[lane]; QB = rp_[l32]; }

    // Prologue: row 0 (init), rows 1,2 (em pipeline), rows 3..10 into slots.
    float zA, zB, tA1, tB1, tA2, tB2;
    ROWLOAD(zA, zB, 0) ROWLOAD(tA1, tB1, 1) ROWLOAD(tA2, tB2, 2)
    float qA3, qB3, qA4, qB4, qA5, qB5, qA6, qB6, qA7, qB7,
          qA0, qB0, qA1, qB1, qA2, qB2;
    ROWLOAD(qA3, qB3, 3) ROWLOAD(qA4, qB4, 4) ROWLOAD(qA5, qB5, 5)
    ROWLOAD(qA6, qB6, 6) ROWLOAD(qA7, qB7, 7)
    ROWLOAD(qA0, qB0, 8) ROWLOAD(qA1, qB1, 9) ROWLOAD(qA2, qB2, 10)

    // em set A = em(1), set B = em(2).
    float eA0 = emit_one(tA1, tB1, c0, h0), eA1 = emit_one(tA1, tB1, c1, h1),
          eA2 = emit_one(tA1, tB1, c2, h2), eA3 = emit_one(tA1, tB1, c3, h3),
          eA4 = emit_one(tA1, tB1, c4, h4), eA5 = emit_one(tA1, tB1, c5, h5),
          eA6 = emit_one(tA1, tB1, c6, h6);
    float eB0 = emit_one(tA2, tB2, c0, h0), eB1 = emit_one(tA2, tB2, c1, h1),
          eB2 = emit_one(tA2, tB2, c2, h2), eB3 = emit_one(tA2, tB2, c3, h3),
          eB4 = emit_one(tA2, tB2, c4, h4), eB5 = emit_one(tA2, tB2, c5, h5),
          eB6 = emit_one(tA2, tB2, c6, h6);

    // alpha(t=0): states 0,1 live (both on lane 0). Linear domain.
    const float e00 = emit_one(zA, zB, c0, h0);
    const float e01 = emit_one(zA, zB, c1, h1);
    float a0v = (lane == 0) ? e00 : 0.0f;
    float a1v = (lane == 0) ? e01 : 0.0f;
    float a2v = 0.0f, a3v = 0.0f, a4v = 0.0f, a5v = 0.0f, a6v = 0.0f;
    float pm1 = 0.0f, pm2 = 0.0f;

    int K = 0, k_cap = 0, t = 1;

#define CAP(J, AJ) { const int s_ = lane * W + (J);                         \
                     if (s_ == ee0) endv[0] = (AJ);                         \
                     if (s_ == ee1) endv[1] = (AJ); }

// Step t: consume em set E (= em(t)); prep em(t+2) into E from row regs
// (QA,QB) = row t+2; reload (QA,QB) with row t+10 (slot distance 8).
#define CTC_STEP(QA, QB, E0, E1, E2, E3, E4, E5, E6)                        \
  {                                                                         \
    const float n6 = fmaf(g6, a4v, a6v + a5v) * E6;                         \
    const float n5 = fmaf(g5, a3v, a5v + a4v) * E5;                         \
    const float npm1 = __shfl_up(n6, 1);   /* consumed NEXT step */         \
    const float npm2 = __shfl_up(n5, 1);                                    \
    const float n4 = fmaf(g4, a2v, a4v + a3v) * E4;                         \
    const float n3 = fmaf(g3, a1v, a3v + a2v) * E3;                         \
    const float n2 = fmaf(g2, a0v, a2v + a1v) * E2;                         \
    const float n1 = fmaf(g1z, pm1, a1v + a0v) * E1;                        \
    const float n0 = fmaf(g0z, pm2, fmaf(zl, pm1, a0v)) * E0;               \
    a6v = n6; a5v = n5; a4v = n4; a3v = n3; a2v = n2; a1v = n1; a0v = n0;   \
    pm1 = npm1; pm2 = npm2;                                                 \
    if (t == inlen - 1) {                                                   \
      CAP(0, a0v); CAP(1, a1v); CAP(2, a2v); CAP(3, a3v);                   \
      CAP(4, a4v); CAP(5, a5v); CAP(6, a6v);                                \
      k_cap = K;                                                            \
    }                                                                       \
    E0 = emit_one(QA, QB, c0, h0); E1 = emit_one(QA, QB, c1, h1);           \
    E2 = emit_one(QA, QB, c2, h2); E3 = emit_one(QA, QB, c3, h3);           \
    E4 = emit_one(QA, QB, c4, h4); E5 = emit_one(QA, QB, c5, h5);           \
    E6 = emit_one(QA, QB, c6, h6);                                          \
    { const int tt = (t + 10 < Tn) ? (t + 10) : (Tn - 1);                   \
      const float* rp_ = src + (size_t)tt * rstride;                        \
      QA = rp_[lane]; QB = rp_[l32]; }                                      \
    ++t;                                                                    \
  }

#define BMAX(J, AJ) { const int s_ = lane * W + (J);                        \
                      if (s_ >= ell && s_ <= ee1) mx = fmaxf(mx, (AJ)); }

    #pragma unroll 1
    for (int c = 0; c < Tn / 8; ++c) {      // 128 chunks -> t = 1..1024
        // slot((t+2)&7) sequence: 3,4,5,6,7,0,1,2 ; em sets alternate A,B.
        CTC_STEP(qA3, qB3, eA0, eA1, eA2, eA3, eA4, eA5, eA6)
        CTC_STEP(qA4, qB4, eB0, eB1, eB2, eB3, eB4, eB5, eB6)
        CTC_STEP(qA5, qB5, eA0, eA1, eA2, eA3, eA4, eA5, eA6)
        CTC_STEP(qA6, qB6, eB0, eB1, eB2, eB3, eB4, eB5, eB6)
        CTC_STEP(qA7, qB7, eA0, eA1, eA2, eA3, eA4, eA5, eA6)
        CTC_STEP(qA0, qB0, eB0, eB1, eB2, eB3, eB4, eB5, eB6)
        CTC_STEP(qA1, qB1, eA0, eA1, eA2, eA3, eA4, eA5, eA6)
        CTC_STEP(qA2, qB2, eB0, eB1, eB2, eB3, eB4, eB5, eB6)

        // ---- band-anchored rescale (exact powers of 2), once per 8 steps ----
        const int ell = (2 * tlen - 1) - 2 * (inlen - t);
        float mx = 0.0f;
        BMAX(0, a0v); BMAX(1, a1v); BMAX(2, a2v); BMAX(3, a3v);
        BMAX(4, a4v); BMAX(5, a5v); BMAX(6, a6v);
        const float mxr = wave_max_dpp_to_lane63(mx);
        const int  smx = __builtin_amdgcn_readlane(__float_as_int(mxr), 63);
        const int  eb  = (smx >> 23) & 0xff;
        const bool nz  = (smx > 0) && (eb < 255);
        const float scale = nz ? __int_as_float((254 - eb) << 23) : 1.0f;
        K += nz ? (127 - eb) : 0;
        a0v *= scale; a1v *= scale; a2v *= scale; a3v *= scale;
        a4v *= scale; a5v *= scale; a6v *= scale;
        pm1 *= scale; pm2 *= scale;
    }

#undef BMAX
#undef CTC_STEP
#undef CAP
#undef ROWLOAD

    __syncthreads();
    if (lane == 0) {
        const float sum = endv[0] + endv[1];
        const float ll2 = flog2(sum) - (float)k_cap;     // log2 of true prob
        float lb = -(ll2 * LN2F);                        // natural-log loss
        if (lb > 1e29f || !(lb == lb)) lb = 0.0f;        // zero_infinity
        out_pb[b] = lb / (float)tlen;                    // mean pre-division
    }
}

// Mean of 128 per-batch losses -> scalar.
__global__ void reduce_mean_kernel(const float* __restrict__ pb,
                                   float* __restrict__ out)
{
    const int l = threadIdx.x;
    float s = pb[l] + pb[l + 64];
    #pragma unroll
    for (int o = 32; o; o >>= 1) s += __shfl_down(s, o);
    if (l == 0) out[0] = s * (1.0f / (float)Bn);
}

extern "C" void kernel_launch(void* const* d_in, const int* in_sizes, int n_in,
                              void* d_out, int out_size, void* d_ws, size_t ws_size,
                              hipStream_t stream)
{
    const float* lp = (const float*)d_in[0];
    const int*   tg = (const int*)d_in[1];
    const int*   il = (const int*)d_in[2];
    const int*   tl = (const int*)d_in[3];
    float* pb  = (float*)d_ws;     // [B] per-batch losses
    float* out = (float*)d_out;    // [1]

    ctc_fused_kernel<<<Bn, 64, 0, stream>>>(lp, tg, il, tl, pb);
    reduce_mean_kernel<<<1, 64, 0, stream>>>(pb, out);
}

// Round 12
// 283.915 us; speedup vs baseline: 1.0426x; 1.0426x over previous
//
#include <hip/hip_runtime.h>

#define LOG2E 1.44269504088896340736f
#define LN2F  0.69314718055994530942f

// Fixed problem sizes from the reference setup_inputs()
constexpr int Tn = 1024;          // time steps
constexpr int Bn = 128;           // batch
constexpr int Cn = 96;            // classes
constexpr int Sn = 200;           // max target length
constexpr int Ln = 2 * Sn + 1;    // extended target length = 401
constexpr int W  = 7;             // states per lane (64*7 = 448 >= 401)

__device__ __forceinline__ float fexp2(float x) {
#if __has_builtin(__builtin_amdgcn_exp2f)
    return __builtin_amdgcn_exp2f(x);
#else
    return exp2f(x);
#endif
}
__device__ __forceinline__ float flog2(float x) {
#if __has_builtin(__builtin_amdgcn_logf)
    return __builtin_amdgcn_logf(x);
#else
    return __log2f(x);
#endif
}

// Wave-wide max via DPP (VALU-latency). Result valid in lane 63.
__device__ __forceinline__ float wave_max_dpp_to_lane63(float x) {
    #define DPP_MAX(ctrl)                                                   \
        x = fmaxf(x, __int_as_float(__builtin_amdgcn_update_dpp(            \
                __float_as_int(x), __float_as_int(x), (ctrl), 0xf, 0xf, false)))
    DPP_MAX(0x111);  // row_shr:1
    DPP_MAX(0x112);  // row_shr:2
    DPP_MAX(0x114);  // row_shr:4
    DPP_MAX(0x118);  // row_shr:8
    DPP_MAX(0x142);  // row_bcast15
    DPP_MAX(0x143);  // row_bcast31 -> lane63 = max(all)
    #undef DPP_MAX
    return x;
}

// ---------------------------------------------------------------------------
// FUSED kernel v2: one wave per batch element, gather + serial recurrence.
// R11 post-mortem: emit_one did shfl -> IMMEDIATE exp/select of the result,
// so each step drained lgkmcnt on 14 fresh bpermutes (525 cyc/step,
// VALUBusy 5.2%). Now a TRUE 3-stage pipeline:
//   stage 1 (step t):   issue 14 raw shfls for row t+2 into RAW regs
//   stage 2 (step t+1): select+exp RAW -> E (RAW is a full step old)
//   stage 3 (step t+2): consume E in the recurrence
// Every ds result is first read ~170 cyc after issue (> ~120 cyc bpermute
// latency). In-step order keeps each lgkmcnt wait referencing only ops from
// the previous step: n's (read pm(t-1)) -> npm issue -> E=exp(RAW(t-1)) ->
// RAW(t) issue. lp rows prefetched 8-deep in named registers. Linear-space
// alpha, band-anchored pow2 rescale, consumer-side lane-0 masking (R8-R10).
// ---------------------------------------------------------------------------
__global__ __launch_bounds__(64, 1) void ctc_fused_kernel(
    const float* __restrict__ lp,   // [T, B, C]
    const int*   __restrict__ tg,   // [B, S]
    const int*   __restrict__ il,   // [B]
    const int*   __restrict__ tl,   // [B]
    float*       __restrict__ out_pb)
{
    const int b    = blockIdx.x;
    const int lane = threadIdx.x;
    __shared__ float endv[2];

    const int inlen = il[b];
    const int tlen  = tl[b];
    const int ee0 = 2 * tlen - 1;
    const int ee1 = 2 * tlen;

    // Per-lane class constants (0 = blank for even/dead states).
    int  c0, c1, c2, c3, c4, c5, c6;       // class index
    int  m0, m1, m2, m3, m4, m5, m6;       // class & 31 (for the hi half)
    bool h0, h1, h2, h3, h4, h5, h6;       // class >= 64 ?
#define MKC(J, CJ, MJ, HJ) { const int s_ = lane * W + (J); int c_ = 0;     \
        if (s_ < Ln && (s_ & 1)) c_ = tg[b * Sn + (s_ >> 1)];               \
        CJ = c_; MJ = c_ & 31; HJ = (c_ >= 64); }
    MKC(0, c0, m0, h0) MKC(1, c1, m1, h1) MKC(2, c2, m2, h2)
    MKC(3, c3, m3, h3) MKC(4, c4, m4, h4) MKC(5, c5, m5, h5)
    MKC(6, c6, m6, h6)
#undef MKC

    // Skip-transition gate per state (1.0 allowed, 0.0 forbidden).
    auto mk_gate = [&](int j) -> float {
        const int s = lane * W + j;
        if (s < Ln && (s & 1) && s >= 3) {
            const int k = s >> 1;
            if (tg[b * Sn + k] != tg[b * Sn + k - 1]) return 1.0f;
        }
        return 0.0f;
    };
    const float g0 = mk_gate(0), g1 = mk_gate(1), g2 = mk_gate(2),
                g3 = mk_gate(3), g4 = mk_gate(4), g5 = mk_gate(5),
                g6 = mk_gate(6);
    const float zl  = (lane == 0) ? 0.0f : 1.0f;
    const float g1z = g1 * zl;
    const float g0z = g0 * zl;

    const float* src = lp + (size_t)b * Cn;
    constexpr size_t rstride = (size_t)Bn * Cn;
    const int l32 = 64 + (lane & 31);   // classes [64,96) duplicated to lanes 32-63

#define ROWLOAD(QA, QB, T) { const float* rp_ = src + (size_t)(T) * rstride; \
        QA = rp_[lane]; QB = rp_[l32]; }

    // Prologue: row 0 (alpha init), row 1 -> E, row 2 -> RAW, rows 3..10 -> Q.
    float zA, zB, tA1, tB1, tA2, tB2;
    ROWLOAD(zA, zB, 0) ROWLOAD(tA1, tB1, 1) ROWLOAD(tA2, tB2, 2)
    float qA3, qB3, qA4, qB4, qA5, qB5, qA6, qB6, qA7, qB7,
          qA0, qB0, qA1, qB1, qA2, qB2;
    ROWLOAD(qA3, qB3, 3) ROWLOAD(qA4, qB4, 4) ROWLOAD(qA5, qB5, 5)
    ROWLOAD(qA6, qB6, 6) ROWLOAD(qA7, qB7, 7)
    ROWLOAD(qA0, qB0, 8) ROWLOAD(qA1, qB1, 9) ROWLOAD(qA2, qB2, 10)

    // E = em(1) (prologue one-time immediate gather is fine).
#define EM1(CJ, MJ, HJ) fexp2(LOG2E * ((HJ) ? __shfl(tB1, (MJ), 64)        \
                                            : __shfl(tA1, (CJ), 64)))
    float e0 = EM1(c0, m0, h0), e1 = EM1(c1, m1, h1), e2 = EM1(c2, m2, h2),
          e3 = EM1(c3, m3, h3), e4 = EM1(c4, m4, h4), e5 = EM1(c5, m5, h5),
          e6 = EM1(c6, m6, h6);
#undef EM1

    // RAW = raw shfls of row 2 (selected+exp'd at step 1, consumed at step 2).
    float rl0 = __shfl(tA2, c0, 64), rh0 = __shfl(tB2, m0, 64),
          rl1 = __shfl(tA2, c1, 64), rh1 = __shfl(tB2, m1, 64),
          rl2 = __shfl(tA2, c2, 64), rh2 = __shfl(tB2, m2, 64),
          rl3 = __shfl(tA2, c3, 64), rh3 = __shfl(tB2, m3, 64),
          rl4 = __shfl(tA2, c4, 64), rh4 = __shfl(tB2, m4, 64),
          rl5 = __shfl(tA2, c5, 64), rh5 = __shfl(tB2, m5, 64),
          rl6 = __shfl(tA2, c6, 64), rh6 = __shfl(tB2, m6, 64);

    // alpha(t=0): states 0,1 live (both on lane 0). Linear domain.
    const float e00 = fexp2(LOG2E * (h0 ? __shfl(zB, m0, 64) : __shfl(zA, c0, 64)));
    const float e01 = fexp2(LOG2E * (h1 ? __shfl(zB, m1, 64) : __shfl(zA, c1, 64)));
    float a0v = (lane == 0) ? e00 : 0.0f;
    float a1v = (lane == 0) ? e01 : 0.0f;
    float a2v = 0.0f, a3v = 0.0f, a4v = 0.0f, a5v = 0.0f, a6v = 0.0f;
    float pm1 = 0.0f, pm2 = 0.0f;

    int K = 0, k_cap = 0, t = 1;

#define CAP(J, AJ) { const int s_ = lane * W + (J);                         \
                     if (s_ == ee0) endv[0] = (AJ);                         \
                     if (s_ == ee1) endv[1] = (AJ); }

// Step t: recurrence consumes E=em(t) and pm(t-1); then E <- exp(RAW(t-1))
// (em(t+1)); then RAW <- shfls of (QA,QB)=row t+2; then reload row t+10.
#define CTC_STEP(QA, QB)                                                    \
  {                                                                         \
    const float n6 = fmaf(g6, a4v, a6v + a5v) * e6;                         \
    const float n5 = fmaf(g5, a3v, a5v + a4v) * e5;                         \
    const float n4 = fmaf(g4, a2v, a4v + a3v) * e4;                         \
    const float n3 = fmaf(g3, a1v, a3v + a2v) * e3;                         \
    const float n2 = fmaf(g2, a0v, a2v + a1v) * e2;                         \
    const float n1 = fmaf(g1z, pm1, a1v + a0v) * e1;                        \
    const float n0 = fmaf(g0z, pm2, fmaf(zl, pm1, a0v)) * e0;               \
    const float npm1 = __shfl_up(n6, 1);   /* consumed NEXT step */         \
    const float npm2 = __shfl_up(n5, 1);                                    \
    a6v = n6; a5v = n5; a4v = n4; a3v = n3; a2v = n2; a1v = n1; a0v = n0;   \
    pm1 = npm1; pm2 = npm2;                                                 \
    if (t == inlen - 1) {                                                   \
      CAP(0, a0v); CAP(1, a1v); CAP(2, a2v); CAP(3, a3v);                   \
      CAP(4, a4v); CAP(5, a5v); CAP(6, a6v);                                \
      k_cap = K;                                                            \
    }                                                                       \
    e0 = fexp2(LOG2E * (h0 ? rh0 : rl0));   /* RAW is one step old */       \
    e1 = fexp2(LOG2E * (h1 ? rh1 : rl1));                                   \
    e2 = fexp2(LOG2E * (h2 ? rh2 : rl2));                                   \
    e3 = fexp2(LOG2E * (h3 ? rh3 : rl3));                                   \
    e4 = fexp2(LOG2E * (h4 ? rh4 : rl4));                                   \
    e5 = fexp2(LOG2E * (h5 ? rh5 : rl5));                                   \
    e6 = fexp2(LOG2E * (h6 ? rh6 : rl6));                                   \
    rl0 = __shfl(QA, c0, 64); rh0 = __shfl(QB, m0, 64);                     \
    rl1 = __shfl(QA, c1, 64); rh1 = __shfl(QB, m1, 64);                     \
    rl2 = __shfl(QA, c2, 64); rh2 = __shfl(QB, m2, 64);                     \
    rl3 = __shfl(QA, c3, 64); rh3 = __shfl(QB, m3, 64);                     \
    rl4 = __shfl(QA, c4, 64); rh4 = __shfl(QB, m4, 64);                     \
    rl5 = __shfl(QA, c5, 64); rh5 = __shfl(QB, m5, 64);                     \
    rl6 = __shfl(QA, c6, 64); rh6 = __shfl(QB, m6, 64);                     \
    { const int tt = (t + 10 < Tn) ? (t + 10) : (Tn - 1);                   \
      const float* rp_ = src + (size_t)tt * rstride;                        \
      QA = rp_[lane]; QB = rp_[l32]; }                                      \
    ++t;                                                                    \
  }

#define BMAX(J, AJ) { const int s_ = lane * W + (J);                        \
                      if (s_ >= ell && s_ <= ee1) mx = fmaxf(mx, (AJ)); }

    #pragma unroll 1
    for (int c = 0; c < Tn / 8; ++c) {      // 128 chunks -> t = 1..1024
        // slot((t+2)&7): 3,4,5,6,7,0,1,2
        CTC_STEP(qA3, qB3) CTC_STEP(qA4, qB4) CTC_STEP(qA5, qB5)
        CTC_STEP(qA6, qB6) CTC_STEP(qA7, qB7) CTC_STEP(qA0, qB0)
        CTC_STEP(qA1, qB1) CTC_STEP(qA2, qB2)

        // ---- band-anchored rescale (exact powers of 2), once per 8 steps ----
        const int ell = (2 * tlen - 1) - 2 * (inlen - t);
        float mx = 0.0f;
        BMAX(0, a0v); BMAX(1, a1v); BMAX(2, a2v); BMAX(3, a3v);
        BMAX(4, a4v); BMAX(5, a5v); BMAX(6, a6v);
        const float mxr = wave_max_dpp_to_lane63(mx);
        const int  smx = __builtin_amdgcn_readlane(__float_as_int(mxr), 63);
        const int  eb  = (smx >> 23) & 0xff;
        const bool nz  = (smx > 0) && (eb < 255);
        const float scale = nz ? __int_as_float((254 - eb) << 23) : 1.0f;
        K += nz ? (127 - eb) : 0;
        a0v *= scale; a1v *= scale; a2v *= scale; a3v *= scale;
        a4v *= scale; a5v *= scale; a6v *= scale;
        pm1 *= scale; pm2 *= scale;
    }

#undef BMAX
#undef CTC_STEP
#undef CAP
#undef ROWLOAD

    __syncthreads();
    if (lane == 0) {
        const float sum = endv[0] + endv[1];
        const float ll2 = flog2(sum) - (float)k_cap;     // log2 of true prob
        float lb = -(ll2 * LN2F);                        // natural-log loss
        if (lb > 1e29f || !(lb == lb)) lb = 0.0f;        // zero_infinity
        out_pb[b] = lb / (float)tlen;                    // mean pre-division
    }
}

// Mean of 128 per-batch losses -> scalar.
__global__ void reduce_mean_kernel(const float* __restrict__ pb,
                                   float* __restrict__ out)
{
    const int l = threadIdx.x;
    float s = pb[l] + pb[l + 64];
    #pragma unroll
    for (int o = 32; o; o >>= 1) s += __shfl_down(s, o);
    if (l == 0) out[0] = s * (1.0f / (float)Bn);
}

extern "C" void kernel_launch(void* const* d_in, const int* in_sizes, int n_in,
                              void* d_out, int out_size, void* d_ws, size_t ws_size,
                              hipStream_t stream)
{
    const float* lp = (const float*)d_in[0];
    const int*   tg = (const int*)d_in[1];
    const int*   il = (const int*)d_in[2];
    const int*   tl = (const int*)d_in[3];
    float* pb  = (float*)d_ws;     // [B] per-batch losses
    float* out = (float*)d_out;    // [1]

    ctc_fused_kernel<<<Bn, 64, 0, stream>>>(lp, tg, il, tl, pb);
    reduce_mean_kernel<<<1, 64, 0, stream>>>(pb, out);
}